// Round 1
// baseline (1619.211 us; speedup 1.0000x reference)
//
#include <hip/hip_runtime.h>
#include <hip/hip_bf16.h>

#define NLAYER 4
#define NHEAD 8
#define CEMB 512
#define HS 64
#define VOCAB_N 32000
#define SEQT 2048
#define BATCH_N 2
#define MROWS (BATCH_N * SEQT)   /* 4096 */
#define WIN 64
#define NGLOB 16
#define NRAND 16

typedef __attribute__((ext_vector_type(8))) __bf16 bf16x8;   // flip to `short` if builtin signature disagrees
typedef __attribute__((ext_vector_type(4))) float f32x4;
typedef __attribute__((ext_vector_type(8))) unsigned short u16x8;

__device__ __forceinline__ unsigned short f2bf(float f) {
    unsigned u = __float_as_uint(f);
    u += 0x7fffu + ((u >> 16) & 1u);      // RNE
    return (unsigned short)(u >> 16);
}

// ---------------------------------------------------------------- transposes
// Wq/Wk/Wv [L,H,C,HS] -> wqkvT [L][n=sel*512+h*64+d][k=c] bf16
__global__ __launch_bounds__(256) void transpose_qkv_kernel(
    const float* __restrict__ Wq, const float* __restrict__ Wk,
    const float* __restrict__ Wv, unsigned short* __restrict__ outT)
{
    __shared__ float t[64][65];
    const int l = blockIdx.z;
    const int sel = blockIdx.y >> 3;
    const int h = blockIdx.y & 7;
    const int c0 = blockIdx.x * 64;
    const float* W = (sel == 0) ? Wq : (sel == 1) ? Wk : Wv;
    const float* in = W + ((size_t)(l * NHEAD + h) * CEMB + c0) * HS;
    const int tid = threadIdx.x;
    #pragma unroll
    for (int i = 0; i < 16; ++i) {
        int idx = tid + i * 256;
        int r = idx >> 6, d = idx & 63;
        t[r][d] = in[r * HS + d];
    }
    __syncthreads();
    unsigned short* out = outT + ((size_t)l * 1536 + sel * 512 + h * 64) * (size_t)CEMB;
    #pragma unroll
    for (int i = 0; i < 16; ++i) {
        int idx = tid + i * 256;
        int d = idx >> 6, r = idx & 63;
        out[(size_t)d * CEMB + c0 + r] = f2bf(t[r][d]);
    }
}

// in [K,N] f32 (batched over z) -> out [N,K] bf16
__global__ __launch_bounds__(256) void transpose_mat_kernel(
    const float* __restrict__ in, unsigned short* __restrict__ out, int K, int N)
{
    __shared__ float t[64][65];
    const size_t zo = (size_t)blockIdx.z * K * N;
    const int k0 = blockIdx.x * 64, n0 = blockIdx.y * 64;
    const int tid = threadIdx.x;
    #pragma unroll
    for (int i = 0; i < 16; ++i) {
        int idx = tid + i * 256;
        int r = idx >> 6, c = idx & 63;
        t[r][c] = in[zo + (size_t)(k0 + r) * N + n0 + c];
    }
    __syncthreads();
    #pragma unroll
    for (int i = 0; i < 16; ++i) {
        int idx = tid + i * 256;
        int c = idx >> 6, r = idx & 63;
        out[zo + (size_t)(n0 + c) * K + k0 + r] = f2bf(t[r][c]);
    }
}

// ---------------------------------------------------------------- embedding
__global__ __launch_bounds__(256) void embed_kernel(
    const float* __restrict__ tok_emb, const float* __restrict__ pos_emb,
    const int* __restrict__ toks, float* __restrict__ x)
{
    int i = blockIdx.x * 256 + threadIdx.x;      // over MROWS*CEMB/4
    int m = i >> 7;
    int c = (i & 127) << 2;
    int tok = toks[m];
    const float4 a = *(const float4*)&tok_emb[(size_t)tok * CEMB + c];
    const float4 p = *(const float4*)&pos_emb[(size_t)(m & (SEQT - 1)) * CEMB + c];
    float4 o;
    o.x = a.x + p.x; o.y = a.y + p.y; o.z = a.z + p.z; o.w = a.w + p.w;
    *(float4*)&x[(size_t)m * CEMB + c] = o;
}

// ---------------------------------------------------------------- layernorm (f32 in -> bf16 out), 1 wave per row
__global__ __launch_bounds__(256) void ln_kernel(
    const float* __restrict__ x, const float* __restrict__ g,
    const float* __restrict__ b, unsigned short* __restrict__ out)
{
    const int wave = threadIdx.x >> 6, lane = threadIdx.x & 63;
    const int m = blockIdx.x * 4 + wave;
    const float* row = x + (size_t)m * CEMB;
    const float4 v0 = *(const float4*)&row[lane * 8];
    const float4 v1 = *(const float4*)&row[lane * 8 + 4];
    float s  = v0.x + v0.y + v0.z + v0.w + v1.x + v1.y + v1.z + v1.w;
    float s2 = v0.x*v0.x + v0.y*v0.y + v0.z*v0.z + v0.w*v0.w
             + v1.x*v1.x + v1.y*v1.y + v1.z*v1.z + v1.w*v1.w;
    #pragma unroll
    for (int off = 32; off > 0; off >>= 1) {
        s  += __shfl_xor(s, off);
        s2 += __shfl_xor(s2, off);
    }
    const float mu  = s * (1.f / CEMB);
    const float var = s2 * (1.f / CEMB) - mu * mu;
    const float rs  = rsqrtf(var + 1e-5f);
    const float vals[8] = {v0.x, v0.y, v0.z, v0.w, v1.x, v1.y, v1.z, v1.w};
    u16x8 o;
    #pragma unroll
    for (int j = 0; j < 8; ++j)
        o[j] = f2bf((vals[j] - mu) * rs * g[lane * 8 + j] + b[lane * 8 + j]);
    *(u16x8*)&out[(size_t)m * CEMB + lane * 8] = o;
}

// ---------------------------------------------------------------- MFMA GEMM
// C[M,N] = A[M,K](bf16) @ B[K,N] (given as Bt[N,K] bf16), 128x128 tile, 4 waves
// MODE 0: f32 out, no bias            (qkv)
// MODE 1: f32 out, +bias, +resid      (proj, mlp2)
// MODE 2: bf16 out, +bias, relu       (mlp1)
// MODE 3: f32 out, +bias              (logits)
template<int MODE>
__global__ __launch_bounds__(256) void gemm_kernel(
    const unsigned short* __restrict__ A, const unsigned short* __restrict__ Bt,
    const float* __restrict__ bias, const float* resid, void* outp,
    int M, int N, int K)
{
    __shared__ unsigned short sa[128][40];   // +8 pad: 80B row stride, conflict-free-ish
    __shared__ unsigned short sb[128][40];
    const int tid = threadIdx.x;
    const int lane = tid & 63;
    const int wave = tid >> 6;
    const int wr = wave >> 1, wc = wave & 1;
    const int m0 = blockIdx.y * 128;
    const int n0 = blockIdx.x * 128;

    f32x4 acc[4][4] = {};

    for (int k0 = 0; k0 < K; k0 += 32) {
        __syncthreads();
        #pragma unroll
        for (int rr = 0; rr < 2; ++rr) {
            int e = (tid + rr * 256) * 8;
            int row = e >> 5, ck = e & 31;
            *(int4*)&sa[row][ck] = *(const int4*)&A[(size_t)(m0 + row) * K + k0 + ck];
            *(int4*)&sb[row][ck] = *(const int4*)&Bt[(size_t)(n0 + row) * K + k0 + ck];
        }
        __syncthreads();
        bf16x8 af[4], bfr[4];
        const int kro = (lane >> 4) * 8;
        #pragma unroll
        for (int i = 0; i < 4; ++i) {
            af[i]  = *reinterpret_cast<const bf16x8*>(&sa[wr * 64 + i * 16 + (lane & 15)][kro]);
            bfr[i] = *reinterpret_cast<const bf16x8*>(&sb[wc * 64 + i * 16 + (lane & 15)][kro]);
        }
        #pragma unroll
        for (int mi = 0; mi < 4; ++mi)
            #pragma unroll
            for (int ni = 0; ni < 4; ++ni)
                acc[mi][ni] = __builtin_amdgcn_mfma_f32_16x16x32_bf16(af[mi], bfr[ni], acc[mi][ni], 0, 0, 0);
    }

    #pragma unroll
    for (int mi = 0; mi < 4; ++mi) {
        #pragma unroll
        for (int ni = 0; ni < 4; ++ni) {
            const int gc = n0 + wc * 64 + ni * 16 + (lane & 15);
            const float bv = (MODE != 0) ? bias[gc] : 0.f;
            #pragma unroll
            for (int r = 0; r < 4; ++r) {
                const int gr = m0 + wr * 64 + mi * 16 + (lane >> 4) * 4 + r;
                float v = acc[mi][ni][r] + bv;
                if (MODE == 1) v += resid[(size_t)gr * N + gc];
                if (MODE == 2) {
                    v = fmaxf(v, 0.f);
                    ((unsigned short*)outp)[(size_t)gr * N + gc] = f2bf(v);
                } else {
                    ((float*)outp)[(size_t)gr * N + gc] = v;
                }
            }
        }
    }
}

// ---------------------------------------------------------------- sparse attention
// qkv [MROWS][1536] f32 (q|k|v each [h*64+d]); one wave per (b,h,t) query.
__global__ __launch_bounds__(256) void attn_kernel(
    const float* __restrict__ qkv, const int* __restrict__ rc,
    unsigned short* __restrict__ attnout)
{
    __shared__ float qs[4][64];
    __shared__ float ews[4][128];
    __shared__ int   ecs[4][128];
    const int wave = threadIdx.x >> 6, lane = threadIdx.x & 63;
    const int bid = blockIdx.x;
    const int tg = bid & 511;
    const int h = (bid >> 9) & 7;
    const int b = bid >> 12;
    const int t = tg * 4 + wave;
    const int m = b * SEQT + t;

    qs[wave][lane] = qkv[(size_t)m * 1536 + h * 64 + lane];
    __syncthreads();

    const float* kb = qkv + (size_t)b * SEQT * 1536 + 512 + h * 64;
    const float* vb = qkv + (size_t)b * SEQT * 1536 + 1024 + h * 64;
    const float* q = qs[wave];

    // slot A: sliding window col = t-63+lane; cols<16 handled by globals
    const int colA = t - 63 + lane;
    const bool vA = (colA >= NGLOB);
    float sA = -1e30f;
    if (vA) {
        const float* kr = kb + (size_t)colA * 1536;
        float s = 0.f;
        #pragma unroll
        for (int j = 0; j < 16; ++j) {
            float4 kv = *(const float4*)&kr[j * 4];
            float4 qv = *(const float4*)&q[j * 4];
            s += kv.x*qv.x + kv.y*qv.y + kv.z*qv.z + kv.w*qv.w;
        }
        sA = s * 0.125f;
    }
    // slot B: lanes 0..15 global cols, lanes 16..31 random cols (dedup'd)
    int colB = 0;
    bool vB = false;
    if (lane < NGLOB) {
        colB = lane;
        vB = (colB <= t);
    } else if (lane < 32) {
        const int i = lane - 16;
        const int* rr = rc + ((size_t)h * SEQT + t) * NRAND;
        const int c = rr[i];
        if (c >= NGLOB && c <= t - WIN) {        // causal + not-window + not-global
            bool dup = false;
            for (int j = 0; j < i; ++j) dup |= (rr[j] == c);
            if (!dup) { vB = true; colB = c; }
        }
    }
    float sB = -1e30f;
    if (vB) {
        const float* kr = kb + (size_t)colB * 1536;
        float s = 0.f;
        #pragma unroll
        for (int j = 0; j < 16; ++j) {
            float4 kv = *(const float4*)&kr[j * 4];
            float4 qv = *(const float4*)&q[j * 4];
            s += kv.x*qv.x + kv.y*qv.y + kv.z*qv.z + kv.w*qv.w;
        }
        sB = s * 0.125f;
    }

    float mx = fmaxf(sA, sB);
    #pragma unroll
    for (int off = 32; off > 0; off >>= 1) mx = fmaxf(mx, __shfl_xor(mx, off));
    const float e0 = vA ? __expf(sA - mx) : 0.f;
    const float e1 = vB ? __expf(sB - mx) : 0.f;
    float sum = e0 + e1;
    #pragma unroll
    for (int off = 32; off > 0; off >>= 1) sum += __shfl_xor(sum, off);

    ews[wave][lane] = e0;       ecs[wave][lane] = vA ? colA : 0;
    ews[wave][64 + lane] = e1;  ecs[wave][64 + lane] = colB;
    __syncthreads();

    const float inv = 1.f / sum;
    float acc = 0.f;
    for (int slot = 0; slot < 128; ++slot) {
        const float w = ews[wave][slot];     // wave-uniform
        if (w != 0.f) {
            const int c = ecs[wave][slot];
            acc += w * vb[(size_t)c * 1536 + lane];
        }
    }
    attnout[(size_t)m * CEMB + h * 64 + lane] = f2bf(acc * inv);
}

// ---------------------------------------------------------------- host
extern "C" void kernel_launch(void* const* d_in, const int* in_sizes, int n_in,
                              void* d_out, int out_size, void* d_ws, size_t ws_size,
                              hipStream_t stream)
{
    const float* tok_emb = (const float*)d_in[0];
    const float* pos_emb = (const float*)d_in[1];
    const float* Wq    = (const float*)d_in[2];
    const float* Wk    = (const float*)d_in[3];
    const float* Wv    = (const float*)d_in[4];
    const float* Wproj = (const float*)d_in[5];
    const float* bproj = (const float*)d_in[6];
    const float* ln1g  = (const float*)d_in[7];
    const float* ln1b  = (const float*)d_in[8];
    const float* ln2g  = (const float*)d_in[9];
    const float* ln2b  = (const float*)d_in[10];
    const float* W1    = (const float*)d_in[11];
    const float* b1    = (const float*)d_in[12];
    const float* W2    = (const float*)d_in[13];
    const float* b2    = (const float*)d_in[14];
    const float* lnfg  = (const float*)d_in[15];
    const float* lnfb  = (const float*)d_in[16];
    const float* Wout  = (const float*)d_in[17];
    const float* bout  = (const float*)d_in[18];
    const int*   toks  = (const int*)d_in[19];
    const int*   rcols = (const int*)d_in[20];
    (void)in_sizes; (void)n_in; (void)out_size; (void)ws_size;

    char* ws = (char*)d_ws;
    size_t off = 0;
    auto ALLOC = [&](size_t bytes) -> void* {
        void* p = ws + off;
        off += (bytes + 255) & ~(size_t)255;
        return p;
    };
    float*          x      = (float*)ALLOC((size_t)MROWS * CEMB * 4);
    unsigned short* xnbf   = (unsigned short*)ALLOC((size_t)MROWS * CEMB * 2);
    float*          qkv    = (float*)ALLOC((size_t)MROWS * 1536 * 4);
    unsigned short* attnbf = (unsigned short*)ALLOC((size_t)MROWS * CEMB * 2);
    unsigned short* hbf    = (unsigned short*)ALLOC((size_t)MROWS * 2048 * 2);
    unsigned short* wqkvT  = (unsigned short*)ALLOC((size_t)NLAYER * 1536 * 512 * 2);
    unsigned short* wprojT = (unsigned short*)ALLOC((size_t)NLAYER * 512 * 512 * 2);
    unsigned short* w1T    = (unsigned short*)ALLOC((size_t)NLAYER * 2048 * 512 * 2);
    unsigned short* w2T    = (unsigned short*)ALLOC((size_t)NLAYER * 512 * 2048 * 2);
    unsigned short* woutT  = (unsigned short*)ALLOC((size_t)VOCAB_N * 512 * 2);

    transpose_qkv_kernel<<<dim3(8, 24, NLAYER), 256, 0, stream>>>(Wq, Wk, Wv, wqkvT);
    transpose_mat_kernel<<<dim3(8, 8, NLAYER),  256, 0, stream>>>(Wproj, wprojT, 512, 512);
    transpose_mat_kernel<<<dim3(8, 32, NLAYER), 256, 0, stream>>>(W1, w1T, 512, 2048);
    transpose_mat_kernel<<<dim3(32, 8, NLAYER), 256, 0, stream>>>(W2, w2T, 2048, 512);
    transpose_mat_kernel<<<dim3(8, 500, 1),     256, 0, stream>>>(Wout, woutT, 512, VOCAB_N);

    embed_kernel<<<2048, 256, 0, stream>>>(tok_emb, pos_emb, toks, x);

    for (int l = 0; l < NLAYER; ++l) {
        ln_kernel<<<1024, 256, 0, stream>>>(x, ln1g + l * CEMB, ln1b + l * CEMB, xnbf);
        gemm_kernel<0><<<dim3(12, 32), 256, 0, stream>>>(
            xnbf, wqkvT + (size_t)l * 1536 * 512, nullptr, nullptr, qkv, MROWS, 1536, 512);
        attn_kernel<<<8192, 256, 0, stream>>>(qkv, rcols + (size_t)l * NHEAD * SEQT * NRAND, attnbf);
        gemm_kernel<1><<<dim3(4, 32), 256, 0, stream>>>(
            attnbf, wprojT + (size_t)l * 512 * 512, bproj + l * CEMB, x, x, MROWS, 512, 512);
        ln_kernel<<<1024, 256, 0, stream>>>(x, ln2g + l * CEMB, ln2b + l * CEMB, xnbf);
        gemm_kernel<2><<<dim3(16, 32), 256, 0, stream>>>(
            xnbf, w1T + (size_t)l * 2048 * 512, b1 + l * 2048, nullptr, hbf, MROWS, 2048, 512);
        gemm_kernel<1><<<dim3(4, 32), 256, 0, stream>>>(
            hbf, w2T + (size_t)l * 512 * 2048, b2 + l * CEMB, x, x, MROWS, 512, 2048);
    }
    ln_kernel<<<1024, 256, 0, stream>>>(x, lnfg, lnfb, xnbf);
    gemm_kernel<3><<<dim3(250, 32), 256, 0, stream>>>(
        xnbf, woutT, bout, nullptr, d_out, MROWS, VOCAB_N, 512);
}

// Round 2
// 1607.928 us; speedup vs baseline: 1.0070x; 1.0070x over previous
//
#include <hip/hip_runtime.h>
#include <hip/hip_bf16.h>

#define NLAYER 4
#define NHEAD 8
#define CEMB 512
#define HS 64
#define VOCAB_N 32000
#define SEQT 2048
#define BATCH_N 2
#define MROWS (BATCH_N * SEQT)   /* 4096 */
#define WIN 64
#define NGLOB 16
#define NRAND 16

typedef __attribute__((ext_vector_type(8))) __bf16 bf16x8;
typedef __attribute__((ext_vector_type(4))) float f32x4;
typedef __attribute__((ext_vector_type(8))) unsigned short u16x8;

__device__ __forceinline__ unsigned short f2bf(float f) {
    unsigned u = __float_as_uint(f);
    u += 0x7fffu + ((u >> 16) & 1u);      // RNE
    return (unsigned short)(u >> 16);
}

// async global->LDS, 16B per lane, dest = wave-uniform base + lane*16
__device__ __forceinline__ void stage16(const unsigned short* g, unsigned short* l) {
    __builtin_amdgcn_global_load_lds(
        (const __attribute__((address_space(1))) void*)g,
        (__attribute__((address_space(3))) void*)l, 16, 0, 0);
}

// ---------------------------------------------------------------- transposes
// Wq/Wk/Wv [L,H,C,HS] -> wqkvT [L][n=sel*512+h*64+d][k=c] bf16
__global__ __launch_bounds__(256) void transpose_qkv_kernel(
    const float* __restrict__ Wq, const float* __restrict__ Wk,
    const float* __restrict__ Wv, unsigned short* __restrict__ outT)
{
    __shared__ float t[64][65];
    const int l = blockIdx.z;
    const int sel = blockIdx.y >> 3;
    const int h = blockIdx.y & 7;
    const int c0 = blockIdx.x * 64;
    const float* W = (sel == 0) ? Wq : (sel == 1) ? Wk : Wv;
    const float* in = W + ((size_t)(l * NHEAD + h) * CEMB + c0) * HS;
    const int tid = threadIdx.x;
    #pragma unroll
    for (int i = 0; i < 16; ++i) {
        int idx = tid + i * 256;
        int r = idx >> 6, d = idx & 63;
        t[r][d] = in[r * HS + d];
    }
    __syncthreads();
    unsigned short* out = outT + ((size_t)l * 1536 + sel * 512 + h * 64) * (size_t)CEMB;
    #pragma unroll
    for (int i = 0; i < 16; ++i) {
        int idx = tid + i * 256;
        int d = idx >> 6, r = idx & 63;
        out[(size_t)d * CEMB + c0 + r] = f2bf(t[r][d]);
    }
}

// in [K,N] f32 (batched over z) -> out [N,K] bf16
__global__ __launch_bounds__(256) void transpose_mat_kernel(
    const float* __restrict__ in, unsigned short* __restrict__ out, int K, int N)
{
    __shared__ float t[64][65];
    const size_t zo = (size_t)blockIdx.z * K * N;
    const int k0 = blockIdx.x * 64, n0 = blockIdx.y * 64;
    const int tid = threadIdx.x;
    #pragma unroll
    for (int i = 0; i < 16; ++i) {
        int idx = tid + i * 256;
        int r = idx >> 6, c = idx & 63;
        t[r][c] = in[zo + (size_t)(k0 + r) * N + n0 + c];
    }
    __syncthreads();
    #pragma unroll
    for (int i = 0; i < 16; ++i) {
        int idx = tid + i * 256;
        int c = idx >> 6, r = idx & 63;
        out[zo + (size_t)(n0 + c) * K + k0 + r] = f2bf(t[r][c]);
    }
}

// ---------------------------------------------------------------- embedding
__global__ __launch_bounds__(256) void embed_kernel(
    const float* __restrict__ tok_emb, const float* __restrict__ pos_emb,
    const int* __restrict__ toks, float* __restrict__ x)
{
    int i = blockIdx.x * 256 + threadIdx.x;      // over MROWS*CEMB/4
    int m = i >> 7;
    int c = (i & 127) << 2;
    int tok = toks[m];
    const float4 a = *(const float4*)&tok_emb[(size_t)tok * CEMB + c];
    const float4 p = *(const float4*)&pos_emb[(size_t)(m & (SEQT - 1)) * CEMB + c];
    float4 o;
    o.x = a.x + p.x; o.y = a.y + p.y; o.z = a.z + p.z; o.w = a.w + p.w;
    *(float4*)&x[(size_t)m * CEMB + c] = o;
}

// ---------------------------------------------------------------- layernorm (f32 in -> bf16 out), 1 wave per row
__global__ __launch_bounds__(256) void ln_kernel(
    const float* __restrict__ x, const float* __restrict__ g,
    const float* __restrict__ b, unsigned short* __restrict__ out)
{
    const int wave = threadIdx.x >> 6, lane = threadIdx.x & 63;
    const int m = blockIdx.x * 4 + wave;
    const float* row = x + (size_t)m * CEMB;
    const float4 v0 = *(const float4*)&row[lane * 8];
    const float4 v1 = *(const float4*)&row[lane * 8 + 4];
    float s  = v0.x + v0.y + v0.z + v0.w + v1.x + v1.y + v1.z + v1.w;
    float s2 = v0.x*v0.x + v0.y*v0.y + v0.z*v0.z + v0.w*v0.w
             + v1.x*v1.x + v1.y*v1.y + v1.z*v1.z + v1.w*v1.w;
    #pragma unroll
    for (int off = 32; off > 0; off >>= 1) {
        s  += __shfl_xor(s, off);
        s2 += __shfl_xor(s2, off);
    }
    const float mu  = s * (1.f / CEMB);
    const float var = s2 * (1.f / CEMB) - mu * mu;
    const float rs  = rsqrtf(var + 1e-5f);
    const float vals[8] = {v0.x, v0.y, v0.z, v0.w, v1.x, v1.y, v1.z, v1.w};
    u16x8 o;
    #pragma unroll
    for (int j = 0; j < 8; ++j)
        o[j] = f2bf((vals[j] - mu) * rs * g[lane * 8 + j] + b[lane * 8 + j]);
    *(u16x8*)&out[(size_t)m * CEMB + lane * 8] = o;
}

// ---------------------------------------------------------------- MFMA GEMM (m97 structure)
// C[M,N] = A[M,K](bf16) @ B[K,N] (given as Bt[N,K] bf16), 128x128 tile, 4 waves,
// BK=32, linear LDS [128][32], global_load_lds width-16 staging, 2 barriers/K-step.
// MODE 0: f32 out, no bias            (qkv)
// MODE 1: f32 out, +bias, +resid      (proj, mlp2)
// MODE 2: bf16 out, +bias, relu       (mlp1)
// MODE 3: f32 out, +bias              (logits)
template<int MODE>
__global__ __launch_bounds__(256) void gemm_kernel(
    const unsigned short* __restrict__ A, const unsigned short* __restrict__ Bt,
    const float* __restrict__ bias, const float* resid, void* outp,
    int M, int N, int K)
{
    __shared__ unsigned short sa[128 * 32];   // linear: elem(row,k) at row*32+k
    __shared__ unsigned short sb[128 * 32];
    const int tid = threadIdx.x;
    const int lane = tid & 63;
    const int wave = tid >> 6;
    const int wr = wave >> 1, wc = wave & 1;
    const int m0 = blockIdx.y * 128;
    const int n0 = blockIdx.x * 128;

    // staging map: chunk c (16B) covers row=c/4, k=(c%4)*8. Wave w owns
    // segments {2w, 2w+1}; within a segment, lane i -> chunk seg*64+i.
    const int c0a = (wave * 2) * 64 + lane;       // chunk for segment 0
    const int c1a = (wave * 2 + 1) * 64 + lane;   // chunk for segment 1
    const int r0 = c0a >> 2, kk0 = (c0a & 3) * 8;
    const int r1 = c1a >> 2, kk1 = (c1a & 3) * 8;
    const unsigned short* ga0 = A  + (size_t)(m0 + r0) * K + kk0;
    const unsigned short* ga1 = A  + (size_t)(m0 + r1) * K + kk1;
    const unsigned short* gb0 = Bt + (size_t)(n0 + r0) * K + kk0;
    const unsigned short* gb1 = Bt + (size_t)(n0 + r1) * K + kk1;
    unsigned short* la0 = &sa[(wave * 2) * 512];
    unsigned short* la1 = &sa[(wave * 2 + 1) * 512];
    unsigned short* lb0 = &sb[(wave * 2) * 512];
    unsigned short* lb1 = &sb[(wave * 2 + 1) * 512];

    f32x4 acc[4][4] = {};
    const int kro = (lane >> 4) * 8;
    const int fr = lane & 15;

    for (int k0 = 0; k0 < K; k0 += 32) {
        __syncthreads();
        stage16(ga0 + k0, la0);
        stage16(ga1 + k0, la1);
        stage16(gb0 + k0, lb0);
        stage16(gb1 + k0, lb1);
        __syncthreads();
        bf16x8 af[4], bfr[4];
        #pragma unroll
        for (int i = 0; i < 4; ++i) {
            af[i]  = *reinterpret_cast<const bf16x8*>(&sa[(wr * 64 + i * 16 + fr) * 32 + kro]);
            bfr[i] = *reinterpret_cast<const bf16x8*>(&sb[(wc * 64 + i * 16 + fr) * 32 + kro]);
        }
        #pragma unroll
        for (int mi = 0; mi < 4; ++mi)
            #pragma unroll
            for (int ni = 0; ni < 4; ++ni)
                acc[mi][ni] = __builtin_amdgcn_mfma_f32_16x16x32_bf16(af[mi], bfr[ni], acc[mi][ni], 0, 0, 0);
    }

    #pragma unroll
    for (int mi = 0; mi < 4; ++mi) {
        #pragma unroll
        for (int ni = 0; ni < 4; ++ni) {
            const int gc = n0 + wc * 64 + ni * 16 + fr;
            const float bv = (MODE != 0) ? bias[gc] : 0.f;
            #pragma unroll
            for (int r = 0; r < 4; ++r) {
                const int gr = m0 + wr * 64 + mi * 16 + (lane >> 4) * 4 + r;
                float v = acc[mi][ni][r] + bv;
                if (MODE == 1) v += resid[(size_t)gr * N + gc];
                if (MODE == 2) {
                    v = fmaxf(v, 0.f);
                    ((unsigned short*)outp)[(size_t)gr * N + gc] = f2bf(v);
                } else {
                    ((float*)outp)[(size_t)gr * N + gc] = v;
                }
            }
        }
    }
}

// ---------------------------------------------------------------- sparse attention
// qkv [MROWS][1536] f32 (q|k|v each [h*64+d]); one wave per (b,h,t) query.
__global__ __launch_bounds__(256) void attn_kernel(
    const float* __restrict__ qkv, const int* __restrict__ rc,
    unsigned short* __restrict__ attnout)
{
    __shared__ float qs[4][64];
    __shared__ float ews[4][128];
    __shared__ int   ecs[4][128];
    const int wave = threadIdx.x >> 6, lane = threadIdx.x & 63;
    const int bid = blockIdx.x;
    const int tg = bid & 511;
    const int h = (bid >> 9) & 7;
    const int b = bid >> 12;
    const int t = tg * 4 + wave;
    const int m = b * SEQT + t;

    qs[wave][lane] = qkv[(size_t)m * 1536 + h * 64 + lane];
    __syncthreads();

    const float* kb = qkv + (size_t)b * SEQT * 1536 + 512 + h * 64;
    const float* vb = qkv + (size_t)b * SEQT * 1536 + 1024 + h * 64;
    const float* q = qs[wave];

    // slot A: sliding window col = t-63+lane; cols<16 handled by globals
    const int colA = t - 63 + lane;
    const bool vA = (colA >= NGLOB);
    float sA = -1e30f;
    if (vA) {
        const float* kr = kb + (size_t)colA * 1536;
        float s = 0.f;
        #pragma unroll
        for (int j = 0; j < 16; ++j) {
            float4 kv = *(const float4*)&kr[j * 4];
            float4 qv = *(const float4*)&q[j * 4];
            s += kv.x*qv.x + kv.y*qv.y + kv.z*qv.z + kv.w*qv.w;
        }
        sA = s * 0.125f;
    }
    // slot B: lanes 0..15 global cols, lanes 16..31 random cols (dedup'd)
    int colB = 0;
    bool vB = false;
    if (lane < NGLOB) {
        colB = lane;
        vB = (colB <= t);
    } else if (lane < 32) {
        const int i = lane - 16;
        const int* rr = rc + ((size_t)h * SEQT + t) * NRAND;
        const int c = rr[i];
        if (c >= NGLOB && c <= t - WIN) {        // causal + not-window + not-global
            bool dup = false;
            for (int j = 0; j < i; ++j) dup |= (rr[j] == c);
            if (!dup) { vB = true; colB = c; }
        }
    }
    float sB = -1e30f;
    if (vB) {
        const float* kr = kb + (size_t)colB * 1536;
        float s = 0.f;
        #pragma unroll
        for (int j = 0; j < 16; ++j) {
            float4 kv = *(const float4*)&kr[j * 4];
            float4 qv = *(const float4*)&q[j * 4];
            s += kv.x*qv.x + kv.y*qv.y + kv.z*qv.z + kv.w*qv.w;
        }
        sB = s * 0.125f;
    }

    float mx = fmaxf(sA, sB);
    #pragma unroll
    for (int off = 32; off > 0; off >>= 1) mx = fmaxf(mx, __shfl_xor(mx, off));
    const float e0 = vA ? __expf(sA - mx) : 0.f;
    const float e1 = vB ? __expf(sB - mx) : 0.f;
    float sum = e0 + e1;
    #pragma unroll
    for (int off = 32; off > 0; off >>= 1) sum += __shfl_xor(sum, off);

    ews[wave][lane] = e0;       ecs[wave][lane] = vA ? colA : 0;
    ews[wave][64 + lane] = e1;  ecs[wave][64 + lane] = colB;
    __syncthreads();

    const float inv = 1.f / sum;
    float acc = 0.f;
    for (int slot = 0; slot < 128; ++slot) {
        const float w = ews[wave][slot];     // wave-uniform
        if (w != 0.f) {
            const int c = ecs[wave][slot];
            acc += w * vb[(size_t)c * 1536 + lane];
        }
    }
    attnout[(size_t)m * CEMB + h * 64 + lane] = f2bf(acc * inv);
}

// ---------------------------------------------------------------- host
extern "C" void kernel_launch(void* const* d_in, const int* in_sizes, int n_in,
                              void* d_out, int out_size, void* d_ws, size_t ws_size,
                              hipStream_t stream)
{
    const float* tok_emb = (const float*)d_in[0];
    const float* pos_emb = (const float*)d_in[1];
    const float* Wq    = (const float*)d_in[2];
    const float* Wk    = (const float*)d_in[3];
    const float* Wv    = (const float*)d_in[4];
    const float* Wproj = (const float*)d_in[5];
    const float* bproj = (const float*)d_in[6];
    const float* ln1g  = (const float*)d_in[7];
    const float* ln1b  = (const float*)d_in[8];
    const float* ln2g  = (const float*)d_in[9];
    const float* ln2b  = (const float*)d_in[10];
    const float* W1    = (const float*)d_in[11];
    const float* b1    = (const float*)d_in[12];
    const float* W2    = (const float*)d_in[13];
    const float* b2    = (const float*)d_in[14];
    const float* lnfg  = (const float*)d_in[15];
    const float* lnfb  = (const float*)d_in[16];
    const float* Wout  = (const float*)d_in[17];
    const float* bout  = (const float*)d_in[18];
    const int*   toks  = (const int*)d_in[19];
    const int*   rcols = (const int*)d_in[20];
    (void)in_sizes; (void)n_in; (void)out_size; (void)ws_size;

    char* ws = (char*)d_ws;
    size_t off = 0;
    auto ALLOC = [&](size_t bytes) -> void* {
        void* p = ws + off;
        off += (bytes + 255) & ~(size_t)255;
        return p;
    };
    float*          x      = (float*)ALLOC((size_t)MROWS * CEMB * 4);
    unsigned short* xnbf   = (unsigned short*)ALLOC((size_t)MROWS * CEMB * 2);
    float*          qkv    = (float*)ALLOC((size_t)MROWS * 1536 * 4);
    unsigned short* attnbf = (unsigned short*)ALLOC((size_t)MROWS * CEMB * 2);
    unsigned short* hbf    = (unsigned short*)ALLOC((size_t)MROWS * 2048 * 2);
    unsigned short* wqkvT  = (unsigned short*)ALLOC((size_t)NLAYER * 1536 * 512 * 2);
    unsigned short* wprojT = (unsigned short*)ALLOC((size_t)NLAYER * 512 * 512 * 2);
    unsigned short* w1T    = (unsigned short*)ALLOC((size_t)NLAYER * 2048 * 512 * 2);
    unsigned short* w2T    = (unsigned short*)ALLOC((size_t)NLAYER * 512 * 2048 * 2);
    unsigned short* woutT  = (unsigned short*)ALLOC((size_t)VOCAB_N * 512 * 2);

    transpose_qkv_kernel<<<dim3(8, 24, NLAYER), 256, 0, stream>>>(Wq, Wk, Wv, wqkvT);
    transpose_mat_kernel<<<dim3(8, 8, NLAYER),  256, 0, stream>>>(Wproj, wprojT, 512, 512);
    transpose_mat_kernel<<<dim3(8, 32, NLAYER), 256, 0, stream>>>(W1, w1T, 512, 2048);
    transpose_mat_kernel<<<dim3(32, 8, NLAYER), 256, 0, stream>>>(W2, w2T, 2048, 512);
    transpose_mat_kernel<<<dim3(8, 500, 1),     256, 0, stream>>>(Wout, woutT, 512, VOCAB_N);

    embed_kernel<<<2048, 256, 0, stream>>>(tok_emb, pos_emb, toks, x);

    for (int l = 0; l < NLAYER; ++l) {
        ln_kernel<<<1024, 256, 0, stream>>>(x, ln1g + l * CEMB, ln1b + l * CEMB, xnbf);
        gemm_kernel<0><<<dim3(12, 32), 256, 0, stream>>>(
            xnbf, wqkvT + (size_t)l * 1536 * 512, nullptr, nullptr, qkv, MROWS, 1536, 512);
        attn_kernel<<<8192, 256, 0, stream>>>(qkv, rcols + (size_t)l * NHEAD * SEQT * NRAND, attnbf);
        gemm_kernel<1><<<dim3(4, 32), 256, 0, stream>>>(
            attnbf, wprojT + (size_t)l * 512 * 512, bproj + l * CEMB, x, x, MROWS, 512, 512);
        ln_kernel<<<1024, 256, 0, stream>>>(x, ln2g + l * CEMB, ln2b + l * CEMB, xnbf);
        gemm_kernel<2><<<dim3(16, 32), 256, 0, stream>>>(
            xnbf, w1T + (size_t)l * 2048 * 512, b1 + l * 2048, nullptr, hbf, MROWS, 2048, 512);
        gemm_kernel<1><<<dim3(4, 32), 256, 0, stream>>>(
            hbf, w2T + (size_t)l * 512 * 2048, b2 + l * CEMB, x, x, MROWS, 512, 2048);
    }
    ln_kernel<<<1024, 256, 0, stream>>>(x, lnfg, lnfb, xnbf);
    gemm_kernel<3><<<dim3(250, 32), 256, 0, stream>>>(
        xnbf, woutT, bout, nullptr, d_out, MROWS, VOCAB_N, 512);
}

// Round 3
// 1356.443 us; speedup vs baseline: 1.1937x; 1.1854x over previous
//
#include <hip/hip_runtime.h>
#include <hip/hip_bf16.h>

#define NLAYER 4
#define NHEAD 8
#define CEMB 512
#define HS 64
#define VOCAB_N 32000
#define SEQT 2048
#define BATCH_N 2
#define MROWS (BATCH_N * SEQT)   /* 4096 */
#define WIN 64
#define NGLOB 16
#define NRAND 16
#define QB 16                    /* queries per attention block */

typedef __attribute__((ext_vector_type(8))) __bf16 bf16x8;
typedef __attribute__((ext_vector_type(4))) float f32x4;
typedef __attribute__((ext_vector_type(8))) unsigned short u16x8;

__device__ __forceinline__ unsigned short f2bf(float f) {
    unsigned u = __float_as_uint(f);
    u += 0x7fffu + ((u >> 16) & 1u);      // RNE
    return (unsigned short)(u >> 16);
}
__device__ __forceinline__ float bf2f(unsigned short v) {
    return __uint_as_float((unsigned)v << 16);
}

// async global->LDS, 16B per lane, dest = wave-uniform base + lane*16
__device__ __forceinline__ void stage16(const unsigned short* g, unsigned short* l) {
    __builtin_amdgcn_global_load_lds(
        (const __attribute__((address_space(1))) void*)g,
        (__attribute__((address_space(3))) void*)l, 16, 0, 0);
}

// ---------------------------------------------------------------- transposes
__global__ __launch_bounds__(256) void transpose_qkv_kernel(
    const float* __restrict__ Wq, const float* __restrict__ Wk,
    const float* __restrict__ Wv, unsigned short* __restrict__ outT)
{
    __shared__ float t[64][65];
    const int l = blockIdx.z;
    const int sel = blockIdx.y >> 3;
    const int h = blockIdx.y & 7;
    const int c0 = blockIdx.x * 64;
    const float* W = (sel == 0) ? Wq : (sel == 1) ? Wk : Wv;
    const float* in = W + ((size_t)(l * NHEAD + h) * CEMB + c0) * HS;
    const int tid = threadIdx.x;
    #pragma unroll
    for (int i = 0; i < 16; ++i) {
        int idx = tid + i * 256;
        int r = idx >> 6, d = idx & 63;
        t[r][d] = in[r * HS + d];
    }
    __syncthreads();
    unsigned short* out = outT + ((size_t)l * 1536 + sel * 512 + h * 64) * (size_t)CEMB;
    #pragma unroll
    for (int i = 0; i < 16; ++i) {
        int idx = tid + i * 256;
        int d = idx >> 6, r = idx & 63;
        out[(size_t)d * CEMB + c0 + r] = f2bf(t[r][d]);
    }
}

__global__ __launch_bounds__(256) void transpose_mat_kernel(
    const float* __restrict__ in, unsigned short* __restrict__ out, int K, int N)
{
    __shared__ float t[64][65];
    const size_t zo = (size_t)blockIdx.z * K * N;
    const int k0 = blockIdx.x * 64, n0 = blockIdx.y * 64;
    const int tid = threadIdx.x;
    #pragma unroll
    for (int i = 0; i < 16; ++i) {
        int idx = tid + i * 256;
        int r = idx >> 6, c = idx & 63;
        t[r][c] = in[zo + (size_t)(k0 + r) * N + n0 + c];
    }
    __syncthreads();
    #pragma unroll
    for (int i = 0; i < 16; ++i) {
        int idx = tid + i * 256;
        int c = idx >> 6, r = idx & 63;
        out[zo + (size_t)(n0 + c) * K + k0 + r] = f2bf(t[r][c]);
    }
}

// ---------------------------------------------------------------- embedding
__global__ __launch_bounds__(256) void embed_kernel(
    const float* __restrict__ tok_emb, const float* __restrict__ pos_emb,
    const int* __restrict__ toks, float* __restrict__ x)
{
    int i = blockIdx.x * 256 + threadIdx.x;
    int m = i >> 7;
    int c = (i & 127) << 2;
    int tok = toks[m];
    const float4 a = *(const float4*)&tok_emb[(size_t)tok * CEMB + c];
    const float4 p = *(const float4*)&pos_emb[(size_t)(m & (SEQT - 1)) * CEMB + c];
    float4 o;
    o.x = a.x + p.x; o.y = a.y + p.y; o.z = a.z + p.z; o.w = a.w + p.w;
    *(float4*)&x[(size_t)m * CEMB + c] = o;
}

// ---------------------------------------------------------------- layernorm
__global__ __launch_bounds__(256) void ln_kernel(
    const float* __restrict__ x, const float* __restrict__ g,
    const float* __restrict__ b, unsigned short* __restrict__ out)
{
    const int wave = threadIdx.x >> 6, lane = threadIdx.x & 63;
    const int m = blockIdx.x * 4 + wave;
    const float* row = x + (size_t)m * CEMB;
    const float4 v0 = *(const float4*)&row[lane * 8];
    const float4 v1 = *(const float4*)&row[lane * 8 + 4];
    float s  = v0.x + v0.y + v0.z + v0.w + v1.x + v1.y + v1.z + v1.w;
    float s2 = v0.x*v0.x + v0.y*v0.y + v0.z*v0.z + v0.w*v0.w
             + v1.x*v1.x + v1.y*v1.y + v1.z*v1.z + v1.w*v1.w;
    #pragma unroll
    for (int off = 32; off > 0; off >>= 1) {
        s  += __shfl_xor(s, off);
        s2 += __shfl_xor(s2, off);
    }
    const float mu  = s * (1.f / CEMB);
    const float var = s2 * (1.f / CEMB) - mu * mu;
    const float rs  = rsqrtf(var + 1e-5f);
    const float vals[8] = {v0.x, v0.y, v0.z, v0.w, v1.x, v1.y, v1.z, v1.w};
    u16x8 o;
    #pragma unroll
    for (int j = 0; j < 8; ++j)
        o[j] = f2bf((vals[j] - mu) * rs * g[lane * 8 + j] + b[lane * 8 + j]);
    *(u16x8*)&out[(size_t)m * CEMB + lane * 8] = o;
}

// ---------------------------------------------------------------- MFMA GEMM (m97 structure)
// MODE 0: bf16 out, no bias           (qkv)
// MODE 1: f32 out, +bias, +resid      (proj, mlp2)
// MODE 2: bf16 out, +bias, relu       (mlp1)
// MODE 3: f32 out, +bias              (logits)
template<int MODE, bool SWZ>
__global__ __launch_bounds__(256) void gemm_kernel(
    const unsigned short* __restrict__ A, const unsigned short* __restrict__ Bt,
    const float* __restrict__ bias, const float* resid, void* outp,
    int M, int N, int K)
{
    __shared__ unsigned short sa[128 * 32];
    __shared__ unsigned short sb[128 * 32];
    const int tid = threadIdx.x;
    const int lane = tid & 63;
    const int wave = tid >> 6;
    const int wr = wave >> 1, wc = wave & 1;

    int bx = blockIdx.x, by = blockIdx.y;
    if (SWZ) {
        const int nx = gridDim.x;
        const int nwg = nx * gridDim.y;
        const int lid = by * nx + bx;
        const int q = nwg >> 3;               // requires nwg % 8 == 0
        const int lid2 = (lid & 7) * q + (lid >> 3);
        by = lid2 / nx; bx = lid2 - by * nx;
    }
    const int m0 = by * 128;
    const int n0 = bx * 128;

    const int c0a = (wave * 2) * 64 + lane;
    const int c1a = (wave * 2 + 1) * 64 + lane;
    const int r0 = c0a >> 2, kk0 = (c0a & 3) * 8;
    const int r1 = c1a >> 2, kk1 = (c1a & 3) * 8;
    const unsigned short* ga0 = A  + (size_t)(m0 + r0) * K + kk0;
    const unsigned short* ga1 = A  + (size_t)(m0 + r1) * K + kk1;
    const unsigned short* gb0 = Bt + (size_t)(n0 + r0) * K + kk0;
    const unsigned short* gb1 = Bt + (size_t)(n0 + r1) * K + kk1;
    unsigned short* la0 = &sa[(wave * 2) * 512];
    unsigned short* la1 = &sa[(wave * 2 + 1) * 512];
    unsigned short* lb0 = &sb[(wave * 2) * 512];
    unsigned short* lb1 = &sb[(wave * 2 + 1) * 512];

    f32x4 acc[4][4] = {};
    const int kro = (lane >> 4) * 8;
    const int fr = lane & 15;

    for (int k0 = 0; k0 < K; k0 += 32) {
        __syncthreads();
        stage16(ga0 + k0, la0);
        stage16(ga1 + k0, la1);
        stage16(gb0 + k0, lb0);
        stage16(gb1 + k0, lb1);
        __syncthreads();
        bf16x8 af[4], bfr[4];
        #pragma unroll
        for (int i = 0; i < 4; ++i) {
            af[i]  = *reinterpret_cast<const bf16x8*>(&sa[(wr * 64 + i * 16 + fr) * 32 + kro]);
            bfr[i] = *reinterpret_cast<const bf16x8*>(&sb[(wc * 64 + i * 16 + fr) * 32 + kro]);
        }
        #pragma unroll
        for (int mi = 0; mi < 4; ++mi)
            #pragma unroll
            for (int ni = 0; ni < 4; ++ni)
                acc[mi][ni] = __builtin_amdgcn_mfma_f32_16x16x32_bf16(af[mi], bfr[ni], acc[mi][ni], 0, 0, 0);
    }

    #pragma unroll
    for (int mi = 0; mi < 4; ++mi) {
        #pragma unroll
        for (int ni = 0; ni < 4; ++ni) {
            const int gc = n0 + wc * 64 + ni * 16 + fr;
            const float bv = (MODE != 0) ? bias[gc] : 0.f;
            #pragma unroll
            for (int r = 0; r < 4; ++r) {
                const int gr = m0 + wr * 64 + mi * 16 + (lane >> 4) * 4 + r;
                float v = acc[mi][ni][r] + bv;
                if (MODE == 1) v += resid[(size_t)gr * N + gc];
                if (MODE == 2) v = fmaxf(v, 0.f);
                if (MODE == 0 || MODE == 2) {
                    ((unsigned short*)outp)[(size_t)gr * N + gc] = f2bf(v);
                } else {
                    ((float*)outp)[(size_t)gr * N + gc] = v;
                }
            }
        }
    }
}

// ---------------------------------------------------------------- sparse attention v2
// qkv [MROWS][1536] bf16 (q|k|v). Block = 16 queries of one (b,h);
// window K/V staged in LDS (K XOR-swizzled); 4 waves x 4 queries each.
__global__ __launch_bounds__(256) void attn_kernel(
    const unsigned short* __restrict__ qkv, const int* __restrict__ rc,
    unsigned short* __restrict__ attnout)
{
    __shared__ unsigned short Kw[80 * 64];   // swizzled 16B chunks
    __shared__ unsigned short Vw[80 * 64];   // linear
    __shared__ float ewA[4][64];
    __shared__ float ewB[4][64];
    __shared__ int   cBs[4][64];

    const int tid = threadIdx.x;
    const int wave = tid >> 6, lane = tid & 63;
    const int bid = blockIdx.x;
    const int tb = bid & 127;            // T/QB = 128
    const int h = (bid >> 7) & 7;
    const int b = bid >> 10;
    const int t0 = tb * QB;
    const int base = t0 - 63;

    const unsigned short* kb = qkv + (size_t)b * SEQT * 1536 + 512 + h * 64;
    const unsigned short* vb = qkv + (size_t)b * SEQT * 1536 + 1024 + h * 64;

    // stage window rows [base, t0+15] (79 rows): K swizzled, V linear
    for (int c = tid; c < 79 * 8; c += 256) {
        const int r = c >> 3, j = c & 7;
        const int col = base + r;
        u16x8 kv = {0, 0, 0, 0, 0, 0, 0, 0};
        u16x8 vv = {0, 0, 0, 0, 0, 0, 0, 0};
        if (col >= 0) {
            kv = *(const u16x8*)&kb[(size_t)col * 1536 + j * 8];
            vv = *(const u16x8*)&vb[(size_t)col * 1536 + j * 8];
        }
        *(u16x8*)&Kw[r * 64 + ((j ^ (r & 7)) * 8)] = kv;
        *(u16x8*)&Vw[r * 64 + j * 8] = vv;
    }
    __syncthreads();

    for (int u = 0; u < 4; ++u) {
        const int Q = wave * 4 + u;
        const int t = t0 + Q;
        const int m = b * SEQT + t;

        // Q row (wave-uniform) in regs
        u16x8 qreg[8];
        #pragma unroll
        for (int j = 0; j < 8; ++j)
            qreg[j] = *(const u16x8*)&qkv[(size_t)m * 1536 + h * 64 + j * 8];

        // slot A: window col = t-63+lane, LDS row = Q+lane
        const int row = Q + lane;
        const int colA = base + row;
        const bool vA = (colA >= NGLOB);
        float sA = -1e30f;
        if (vA) {
            float s = 0.f;
            #pragma unroll
            for (int j = 0; j < 8; ++j) {
                const u16x8 kc = *(const u16x8*)&Kw[row * 64 + ((j ^ (row & 7)) * 8)];
                #pragma unroll
                for (int e = 0; e < 8; ++e)
                    s += bf2f(kc[e]) * bf2f(qreg[j][e]);
            }
            sA = s * 0.125f;
        }

        // slot B: lanes 0..15 global, 16..31 random (dedup'd)
        int colB = 0;
        bool vB = false;
        if (lane < NGLOB) {
            colB = lane;
            vB = (colB <= t);
        } else if (lane < 32) {
            const int i = lane - 16;
            const int* rr = rc + ((size_t)h * SEQT + t) * NRAND;
            const int cc = rr[i];
            if (cc >= NGLOB && cc <= t - WIN) {
                bool dup = false;
                for (int j2 = 0; j2 < i; ++j2) dup |= (rr[j2] == cc);
                if (!dup) { vB = true; colB = cc; }
            }
        }
        float sB = -1e30f;
        if (vB) {
            float s = 0.f;
            const unsigned short* kr = &kb[(size_t)colB * 1536];
            #pragma unroll
            for (int j = 0; j < 8; ++j) {
                const u16x8 kc = *(const u16x8*)&kr[j * 8];
                #pragma unroll
                for (int e = 0; e < 8; ++e)
                    s += bf2f(kc[e]) * bf2f(qreg[j][e]);
            }
            sB = s * 0.125f;
        }

        // softmax over the wave
        float mx = fmaxf(sA, sB);
        #pragma unroll
        for (int off = 32; off > 0; off >>= 1) mx = fmaxf(mx, __shfl_xor(mx, off));
        const float e0 = vA ? __expf(sA - mx) : 0.f;
        const float e1 = vB ? __expf(sB - mx) : 0.f;
        float sum = e0 + e1;
        #pragma unroll
        for (int off = 32; off > 0; off >>= 1) sum += __shfl_xor(sum, off);

        ewA[wave][lane] = e0;
        ewB[wave][lane] = e1;
        cBs[wave][lane] = colB;
        __syncthreads();   // LDS visibility (cross-lane within wave) + cheap

        const float inv = 1.f / sum;
        float acc = 0.f;
        // window PV: branch-free, V from LDS (invalid rows staged as 0 or weight 0)
        #pragma unroll 4
        for (int s = 0; s < 64; ++s) {
            const float wgt = ewA[wave][s];
            acc += wgt * bf2f(Vw[(Q + s) * 64 + lane]);
        }
        // global+random PV: wave-uniform skip of dead slots
        for (int s = 0; s < 64; ++s) {
            const float wgt = ewB[wave][s];
            if (wgt != 0.f) {
                const int cc = cBs[wave][s];
                acc += wgt * bf2f(vb[(size_t)cc * 1536 + lane]);
            }
        }
        attnout[(size_t)m * CEMB + h * 64 + lane] = f2bf(acc * inv);
        __syncthreads();   // protect ewA/ewB before next query overwrites
    }
}

// ---------------------------------------------------------------- host
extern "C" void kernel_launch(void* const* d_in, const int* in_sizes, int n_in,
                              void* d_out, int out_size, void* d_ws, size_t ws_size,
                              hipStream_t stream)
{
    const float* tok_emb = (const float*)d_in[0];
    const float* pos_emb = (const float*)d_in[1];
    const float* Wq    = (const float*)d_in[2];
    const float* Wk    = (const float*)d_in[3];
    const float* Wv    = (const float*)d_in[4];
    const float* Wproj = (const float*)d_in[5];
    const float* bproj = (const float*)d_in[6];
    const float* ln1g  = (const float*)d_in[7];
    const float* ln1b  = (const float*)d_in[8];
    const float* ln2g  = (const float*)d_in[9];
    const float* ln2b  = (const float*)d_in[10];
    const float* W1    = (const float*)d_in[11];
    const float* b1    = (const float*)d_in[12];
    const float* W2    = (const float*)d_in[13];
    const float* b2    = (const float*)d_in[14];
    const float* lnfg  = (const float*)d_in[15];
    const float* lnfb  = (const float*)d_in[16];
    const float* Wout  = (const float*)d_in[17];
    const float* bout  = (const float*)d_in[18];
    const int*   toks  = (const int*)d_in[19];
    const int*   rcols = (const int*)d_in[20];
    (void)in_sizes; (void)n_in; (void)out_size; (void)ws_size;

    char* ws = (char*)d_ws;
    size_t off = 0;
    auto ALLOC = [&](size_t bytes) -> void* {
        void* p = ws + off;
        off += (bytes + 255) & ~(size_t)255;
        return p;
    };
    float*          x      = (float*)ALLOC((size_t)MROWS * CEMB * 4);
    unsigned short* xnbf   = (unsigned short*)ALLOC((size_t)MROWS * CEMB * 2);
    unsigned short* qkv    = (unsigned short*)ALLOC((size_t)MROWS * 1536 * 2);
    unsigned short* attnbf = (unsigned short*)ALLOC((size_t)MROWS * CEMB * 2);
    unsigned short* hbf    = (unsigned short*)ALLOC((size_t)MROWS * 2048 * 2);
    unsigned short* wqkvT  = (unsigned short*)ALLOC((size_t)NLAYER * 1536 * 512 * 2);
    unsigned short* wprojT = (unsigned short*)ALLOC((size_t)NLAYER * 512 * 512 * 2);
    unsigned short* w1T    = (unsigned short*)ALLOC((size_t)NLAYER * 2048 * 512 * 2);
    unsigned short* w2T    = (unsigned short*)ALLOC((size_t)NLAYER * 512 * 2048 * 2);
    unsigned short* woutT  = (unsigned short*)ALLOC((size_t)VOCAB_N * 512 * 2);

    transpose_qkv_kernel<<<dim3(8, 24, NLAYER), 256, 0, stream>>>(Wq, Wk, Wv, wqkvT);
    transpose_mat_kernel<<<dim3(8, 8, NLAYER),  256, 0, stream>>>(Wproj, wprojT, 512, 512);
    transpose_mat_kernel<<<dim3(8, 32, NLAYER), 256, 0, stream>>>(W1, w1T, 512, 2048);
    transpose_mat_kernel<<<dim3(32, 8, NLAYER), 256, 0, stream>>>(W2, w2T, 2048, 512);
    transpose_mat_kernel<<<dim3(8, 500, 1),     256, 0, stream>>>(Wout, woutT, 512, VOCAB_N);

    embed_kernel<<<2048, 256, 0, stream>>>(tok_emb, pos_emb, toks, x);

    for (int l = 0; l < NLAYER; ++l) {
        ln_kernel<<<1024, 256, 0, stream>>>(x, ln1g + l * CEMB, ln1b + l * CEMB, xnbf);
        gemm_kernel<0, false><<<dim3(12, 32), 256, 0, stream>>>(
            xnbf, wqkvT + (size_t)l * 1536 * 512, nullptr, nullptr, qkv, MROWS, 1536, 512);
        attn_kernel<<<2048, 256, 0, stream>>>(qkv, rcols + (size_t)l * NHEAD * SEQT * NRAND, attnbf);
        gemm_kernel<1, false><<<dim3(4, 32), 256, 0, stream>>>(
            attnbf, wprojT + (size_t)l * 512 * 512, bproj + l * CEMB, x, x, MROWS, 512, 512);
        ln_kernel<<<1024, 256, 0, stream>>>(x, ln2g + l * CEMB, ln2b + l * CEMB, xnbf);
        gemm_kernel<2, false><<<dim3(16, 32), 256, 0, stream>>>(
            xnbf, w1T + (size_t)l * 2048 * 512, b1 + l * 2048, nullptr, hbf, MROWS, 2048, 512);
        gemm_kernel<1, false><<<dim3(4, 32), 256, 0, stream>>>(
            hbf, w2T + (size_t)l * 512 * 2048, b2 + l * CEMB, x, x, MROWS, 512, 2048);
    }
    ln_kernel<<<1024, 256, 0, stream>>>(x, lnfg, lnfb, xnbf);
    gemm_kernel<3, true><<<dim3(250, 32), 256, 0, stream>>>(
        xnbf, woutT, bout, nullptr, d_out, MROWS, VOCAB_N, 512);
}